// Round 6
// baseline (212.608 us; speedup 1.0000x reference)
//
#include <hip/hip_runtime.h>

#define NN 400
#define HID 96
#define EDGES 79800
#define BATCH 16
#define ROWS (BATCH*EDGES)
#define NTILES 4988
#define NBLK 1024

typedef _Float16 f16;
typedef f16 f16x2 __attribute__((ext_vector_type(2)));
typedef f16 f16x8 __attribute__((ext_vector_type(8)));
typedef __fp16 fp16x2 __attribute__((ext_vector_type(2)));
typedef float f32x16 __attribute__((ext_vector_type(16)));
typedef unsigned int u32;
typedef unsigned long long u64;

union H8 { f16x8 h; u32 u[4]; f16x2 p[4]; fp16x2 q[4]; u64 d[2]; };
union C2 { f16x2 h; fp16x2 q; u32 u; };
union A16 { f32x16 v; float4 f[4]; };

__device__ inline f16x2 pkrtz(float a, float b) {
  C2 c; c.q = __builtin_amdgcn_cvt_pkrtz(a, b); return c.h;
}
__device__ inline u32 pkrtz_u(float a, float b) {
  C2 c; c.q = __builtin_amdgcn_cvt_pkrtz(a, b); return c.u;
}
__device__ inline float fdot2a(f16x2 a, f16x2 b, float c) {
#if __has_builtin(__builtin_amdgcn_fdot2)
  C2 ca, cb; ca.h = a; cb.h = b;
  return __builtin_amdgcn_fdot2(ca.q, cb.q, c, false);
#else
  return c + (float)a.x*(float)b.x + (float)a.y*(float)b.y;
#endif
}

__device__ inline f16x8 habs8(f16x8 x) {
  H8 t; t.h = x;
  t.u[0] &= 0x7fff7fffu; t.u[1] &= 0x7fff7fffu;
  t.u[2] &= 0x7fff7fffu; t.u[3] &= 0x7fff7fffu;
  return t.h;
}

__device__ inline f16x8 pack8(float a0,float a1,float a2,float a3,
                              float a4,float a5,float a6,float a7){
  H8 u;
  u.p[0] = pkrtz(a0,a1);
  u.p[1] = pkrtz(a2,a3);
  u.p[2] = pkrtz(a4,a5);
  u.p[3] = pkrtz(a6,a7);
  return u.h;
}

// ---------------- fused prep (blocks 0..139) + per-batch partial mean (blocks 140..395) --------
// wq regions (dwords): Wd1 [0,9216)  Wd2-permK [9216,11264)  We1 [11264,31232)  We2 [31232,35840)
// mpart[256]: 16 partial sums per batch.
__global__ void prep_mean_kernel(const float* __restrict__ We1, const float* __restrict__ We2,
                                 const float* __restrict__ W1, const float* __restrict__ W2,
                                 const float* __restrict__ sc,
                                 u32* __restrict__ wq, float* __restrict__ mpart) {
  if (blockIdx.x >= 140) {
    int p = blockIdx.x - 140;           // 0..255
    int b = p >> 4, part = p & 15;
    const float4* src = (const float4*)(sc + (size_t)b*160000) + part*2500;
    float s = 0.f;
    for (int i = threadIdx.x; i < 2500; i += 256) {
      float4 v = src[i];
      s += (v.x + v.y) + (v.z + v.w);
    }
    __shared__ float red[256];
    red[threadIdx.x] = s; __syncthreads();
    for (int off = 128; off > 0; off >>= 1) {
      if (threadIdx.x < off) red[threadIdx.x] += red[threadIdx.x + off];
      __syncthreads();
    }
    if (threadIdx.x == 0) mpart[p] = red[0];
    return;
  }
  int D = blockIdx.x*256 + threadIdx.x;     // 0..35839
  float v0, v1;
  if (D < 9216) {               // W_d1 B-frags (288 x 64), d = 32q+c
    int frag = D >> 8;  int t = frag >> 1, q = frag & 1;
    int rem = D & 255;  int lane = rem >> 2, dj = rem & 3;
    int c = lane & 31, h2 = lane >> 5;
    int k = 16*t + 8*h2 + 2*dj;
    int d = 32*q + c;
    v0 = W1[k*64 + d]; v1 = W1[(k+1)*64 + d];
  } else if (D < 11264) {       // W_d2 B-frags, K permuted: pair sources (p, p+32)
    int Dl = D - 9216;
    int frag = Dl >> 8; int t2 = frag >> 1, q = frag & 1;
    int rem = Dl & 255; int lane = rem >> 2, dj = rem & 3;
    int c = lane & 31, h2 = lane >> 5;
    int p = 8*t2 + 4*h2 + dj;
    int d = 32*q + c;
    v0 = W2[p*64 + d]; v1 = W2[(p+32)*64 + d];
  } else if (D < 31232) {       // W_e1 frags (416 x 96), feature-permuted (sc first, static at 400)
    int Dl = D - 11264;
    int frag = Dl >> 8; int t = frag/3, ct = frag - 3*t;
    int rem = Dl & 255; int lane = rem >> 2, dj = rem & 3;
    int c = lane & 31, h2 = lane >> 5;
    int k0 = 16*t + 8*h2 + 2*dj, k1 = k0 + 1;
    int d = 32*ct + c;
    v0 = (k0 < 400) ? We1[(8+k0)*96 + d] : (k0 < 408 ? We1[(k0-400)*96 + d] : 0.f);
    v1 = (k1 < 400) ? We1[(8+k1)*96 + d] : (k1 < 408 ? We1[(k1-400)*96 + d] : 0.f);
  } else {                      // W_e2 frags (96 x 96), plain K order
    int Dl = D - 31232;
    int frag = Dl >> 8; int t = frag/3, ct = frag - 3*t;
    int rem = Dl & 255; int lane = rem >> 2, dj = rem & 3;
    int c = lane & 31, h2 = lane >> 5;
    int k = 16*t + 8*h2 + 2*dj;
    int d = 32*ct + c;
    v0 = We2[k*96 + d]; v1 = We2[(k+1)*96 + d];
  }
  wq[D] = pkrtz_u(v0, v1);
}

// ---------------- fused encoder, K-split across 4 waves ----------------
// 200 blocks x 256 threads; block = 32 rows. Phases:
//  stage sc tile -> LDS f16 (coalesced, all threads)  |  L1 partial GEMM (wave w: kstep quarter)
//  -> f32 partial reduce via LDS  |  prelu+transpose z1  |  L2 (waves 0..2, one col-tile each)
__global__ __launch_bounds__(256) void enc_kernel(
    const float* __restrict__ sc, const float* __restrict__ nf,
    const float* __restrict__ smean, const float* __restrict__ sstd,
    const float* __restrict__ be1, const float* __restrict__ ae1,
    const float* __restrict__ be2, const float* __restrict__ ae2,
    const float* __restrict__ mpart, const u32* __restrict__ wq,
    f16* __restrict__ hout) {
  __shared__ u32 lds[12288 + 1664];   // stage(6720)/red(12288) overlay + zb(1664) = 55,808 B
  const int tid = threadIdx.x;
  const int wid = tid >> 6, lane = tid & 63;
  const int c = lane & 31, h2 = lane >> 5;
  const int r0 = blockIdx.x * 32;
  // ---- stage: 32 rows x 400 f32 -> f16 (scaled by rm), row stride 210 dwords ----
  {
    int row = tid >> 3, seg = tid & 7;
    int r = r0 + row;
    int b = r / 400;
    float ms = 0.f;
    const float4* mp4 = (const float4*)(mpart + 16*b);
#pragma unroll
    for (int k = 0; k < 4; ++k) { float4 v = mp4[k]; ms += (v.x+v.y)+(v.z+v.w); }
    float rm = 1.f / fmaxf(ms*(1.f/160000.f), 1e-8f);
    const float4* src = (const float4*)(sc + (size_t)r*400);
#pragma unroll
    for (int i = 0; i < 13; ++i) {
      int col4 = seg + 8*i;
      if (col4 < 100) {
        float4 v = src[col4];
        u32 lo = pkrtz_u(v.x*rm, v.y*rm);
        u32 hi = pkrtz_u(v.z*rm, v.w*rm);
        *(u64*)(lds + row*210 + col4*2) = (u64)lo | ((u64)hi << 32);
      }
    }
  }
  __syncthreads();
  // ---- L1 partial: wave w handles ksteps [tb,te) of 26 ----
  int tb = (wid==0) ? 0 : (wid==1) ? 7 : (wid==2) ? 14 : 20;
  int te = (wid==0) ? 7 : (wid==1) ? 14 : (wid==2) ? 20 : 26;
  f32x16 acc[3] = {};
  const u32* wb1 = wq + 11264;
  for (int t = tb; t < te; ++t) {
    f16x8 af;
    if (t < 25) {
      H8 av;
      const u32* ap = lds + c*210 + 8*t + 4*h2;
      av.d[0] = *(const u64*)ap;
      av.d[1] = *(const u64*)(ap + 2);
      af = av.h;
    } else {
      af = (f16x8){};
      if (h2 == 0) {
        int r = r0 + c;
        float q0[8];
#pragma unroll
        for (int j = 0; j < 8; ++j)
          q0[j] = (nf[r*8 + j] - smean[j]) / (sstd[j] + 1e-8f);
        af = pack8(q0[0],q0[1],q0[2],q0[3],q0[4],q0[5],q0[6],q0[7]);
      }
    }
#pragma unroll
    for (int ct = 0; ct < 3; ++ct) {
      f16x8 bf = *(const f16x8*)(wb1 + ((t*3+ct)*64 + lane)*4);
      acc[ct] = __builtin_amdgcn_mfma_f32_32x32x16_f16(af, bf, acc[ct], 0,0,0);
    }
  }
  __syncthreads();   // st reads done; red overlays st
  // ---- write partials: set = wid*3+ct, layout ((set*4+i4)*64+lane)*4 (wfr-proven pattern) ----
#pragma unroll
  for (int ct = 0; ct < 3; ++ct) {
    A16 u; u.v = acc[ct];
#pragma unroll
    for (int i4 = 0; i4 < 4; ++i4)
      *(float4*)(lds + (((wid*3+ct)*4 + i4)*64 + lane)*4) = u.f[i4];
  }
  __syncthreads();
  f16* zb16 = (f16*)(lds + 12288);
  const float a1 = *ae1;
  if (wid < 3) {
    float bv = be1[32*wid + c];
    f32x16 s;
#pragma unroll
    for (int i = 0; i < 16; ++i) s[i] = bv;
#pragma unroll
    for (int w2 = 0; w2 < 4; ++w2) {
#pragma unroll
      for (int i4 = 0; i4 < 4; ++i4) {
        float4 f = *(const float4*)(lds + (((w2*3+wid)*4 + i4)*64 + lane)*4);
        s[4*i4+0] += f.x; s[4*i4+1] += f.y; s[4*i4+2] += f.z; s[4*i4+3] += f.w;
      }
    }
    // prelu + transpose: zb16[edge_row][96(+8 pad)] plain d order
#pragma unroll
    for (int r = 0; r < 16; ++r) {
      float v = s[r]; v = fmaxf(v, a1*v);
      int row = (r & 3) + 8*(r >> 2) + 4*h2;
      zb16[row*104 + 32*wid + c] = (f16)v;
    }
  }
  __syncthreads();
  // ---- L2: waves 0..2, col-tile = wid ----
  if (wid < 3) {
    const float a2 = *ae2;
    float bv = be2[32*wid + c];
    f32x16 acc2;
#pragma unroll
    for (int i = 0; i < 16; ++i) acc2[i] = bv;
    const u32* wb2 = wq + 31232;
#pragma unroll
    for (int t = 0; t < 6; ++t) {
      f16x8 af = *(const f16x8*)(zb16 + c*104 + 16*t + 8*h2);
      f16x8 bf = *(const f16x8*)(wb2 + ((t*3+wid)*64 + lane)*4);
      acc2 = __builtin_amdgcn_mfma_f32_32x32x16_f16(af, bf, acc2, 0,0,0);
    }
#pragma unroll
    for (int rr = 0; rr < 16; ++rr) {
      int row = (rr & 3) + 8*(rr >> 2) + 4*h2;
      float v = acc2[rr]; v = fmaxf(v, a2*v);
      hout[(r0 + row)*96 + 32*wid + c] = (f16)v;
    }
  }
}

// ---------------- decoder: barrier-free, B-frags from L2, LDS = per-wave zbuf only --------------
// LDS 18,432 B -> residency VGPR-capped (~4 blocks/CU), no __syncthreads anywhere.
// Per-iteration memory clobber stops LICM from hoisting 34 loop-invariant B-frag loads (spill guard).
__global__ __launch_bounds__(256, 2) void decoder_kernel(
    const f16* __restrict__ hbuf, const u32* __restrict__ wq,
    const float* __restrict__ b1, const float* __restrict__ b2,
    const float* __restrict__ ad1, const float* __restrict__ ad2,
    const float* __restrict__ W3, const float* __restrict__ b3p,
    const int* __restrict__ ei, const int* __restrict__ ej,
    float* __restrict__ out) {
  __shared__ u32 zbuf[4][1152];       // per-wave z staging: 18,432 B
  const int lane = threadIdx.x & 63;
  const int wid  = threadIdx.x >> 6;
  const int c = lane & 31, h2 = lane >> 5;
  u32* zb = zbuf[wid];
  f16x8 w2f[4][2];
#pragma unroll
  for (int t2 = 0; t2 < 4; ++t2) {
    w2f[t2][0] = *(const f16x8*)(wq + 9216 + ((t2*2+0)*64 + lane)*4);
    w2f[t2][1] = *(const f16x8*)(wq + 9216 + ((t2*2+1)*64 + lane)*4);
  }
  const float b1x = b1[c], b1y = b1[c+32];
  const float b2x = b2[c], b2y = b2[c+32];
  const float a1 = *ad1, a2 = *ad2, b3 = *b3p;
  const f16x2 a1v = pkrtz(a1, a1);
  const f16x2 a2v = pkrtz(a2, a2);
  const f16x2 w3p = pkrtz(W3[c], W3[c+32]);
  const f16x2 ones2 = pkrtz(1.f, 1.f);

  int tile = blockIdx.x;
  int nii[2], njj[2]; bool nvalid[2];
#pragma unroll
  for (int m = 0; m < 2; ++m) {
    int r = tile*256 + wid*64 + 32*m + c;
    nvalid[m] = (r < ROWS);
    unsigned rr = nvalid[m] ? (unsigned)r : (unsigned)(ROWS-1);
    unsigned bb = rr / (unsigned)EDGES;
    int e = (int)(rr - bb*(unsigned)EDGES);
    nii[m] = (int)(bb*NN) + ei[e];
    njj[m] = (int)(bb*NN) + ej[e];
  }

  for (; tile < NTILES; tile += NBLK) {
    asm volatile("" ::: "memory");    // defeat cross-iteration CSE/LICM of B-frag loads
    const int rbase = tile*256 + wid*64;
    const f16* pi[2]; const f16* pj[2];
    bool valid[2];
#pragma unroll
    for (int m = 0; m < 2; ++m) {
      valid[m] = nvalid[m];
      pi[m] = hbuf + (nii[m]*HID + 8*h2);
      pj[m] = hbuf + (njj[m]*HID + 8*h2);
    }
    int ntile = tile + NBLK;
    if (ntile < NTILES) {
#pragma unroll
      for (int m = 0; m < 2; ++m) {
        int r = ntile*256 + wid*64 + 32*m + c;
        nvalid[m] = (r < ROWS);
        unsigned rr = nvalid[m] ? (unsigned)r : (unsigned)(ROWS-1);
        unsigned bb = rr / (unsigned)EDGES;
        int e = (int)(rr - bb*(unsigned)EDGES);
        nii[m] = (int)(bb*NN) + ei[e];
        njj[m] = (int)(bb*NN) + ej[e];
      }
    }
    f32x16 acc[2][2];
#pragma unroll
    for (int r = 0; r < 16; ++r) {
      acc[0][0][r] = b1x; acc[0][1][r] = b1y;
      acc[1][0][r] = b1x; acc[1][1][r] = b1y;
    }
    // layer 1: K=288 = 6 octet-steps x {sum, absdiff, prod}; B-frags from L2
#pragma unroll
    for (int t = 0; t < 6; ++t) {
      f16x8 bs0 = *(const f16x8*)(wq + (((t   )*2+0)*64 + lane)*4);
      f16x8 bs1 = *(const f16x8*)(wq + (((t   )*2+1)*64 + lane)*4);
      f16x8 bd0 = *(const f16x8*)(wq + (((t+ 6)*2+0)*64 + lane)*4);
      f16x8 bd1 = *(const f16x8*)(wq + (((t+ 6)*2+1)*64 + lane)*4);
      f16x8 bp0 = *(const f16x8*)(wq + (((t+12)*2+0)*64 + lane)*4);
      f16x8 bp1 = *(const f16x8*)(wq + (((t+12)*2+1)*64 + lane)*4);
#pragma unroll
      for (int m = 0; m < 2; ++m) {
        f16x8 hi = *(const f16x8*)(pi[m] + 16*t);
        f16x8 hj = *(const f16x8*)(pj[m] + 16*t);
        f16x8 su = hi + hj;
        f16x8 di = habs8(hi - hj);
        f16x8 pr = hi * hj;
        acc[m][0] = __builtin_amdgcn_mfma_f32_32x32x16_f16(su, bs0, acc[m][0], 0,0,0);
        acc[m][1] = __builtin_amdgcn_mfma_f32_32x32x16_f16(su, bs1, acc[m][1], 0,0,0);
        acc[m][0] = __builtin_amdgcn_mfma_f32_32x32x16_f16(di, bd0, acc[m][0], 0,0,0);
        acc[m][1] = __builtin_amdgcn_mfma_f32_32x32x16_f16(di, bd1, acc[m][1], 0,0,0);
        acc[m][0] = __builtin_amdgcn_mfma_f32_32x32x16_f16(pr, bp0, acc[m][0], 0,0,0);
        acc[m][1] = __builtin_amdgcn_mfma_f32_32x32x16_f16(pr, bp1, acc[m][1], 0,0,0);
      }
    }
#pragma unroll
    for (int m = 0; m < 2; ++m) {
      // prelu(z1) packed-f16 -> LDS pairs (d, d+32) at dword [row][c], stride 36
#pragma unroll
      for (int r = 0; r < 16; ++r) {
        f16x2 p = pkrtz(acc[m][0][r], acc[m][1][r]);
        p = __builtin_elementwise_max(p, p * a1v);
        C2 cv; cv.h = p;
        int row = (r & 3) + 8*(r >> 2) + 4*h2;
        zb[row*36 + c] = cv.u;
      }
      // read back as layer-2 A-frags (edge = c): permuted-K contiguous, aligned b128
      f16x8 za[4];
#pragma unroll
      for (int t2 = 0; t2 < 4; ++t2)
        za[t2] = *(const f16x8*)((const f16*)zb + (c*36 + 8*t2 + 4*h2)*2);
      f32x16 zacc[2];
#pragma unroll
      for (int r = 0; r < 16; ++r) { zacc[0][r] = b2x; zacc[1][r] = b2y; }
#pragma unroll
      for (int t2 = 0; t2 < 4; ++t2) {
        zacc[0] = __builtin_amdgcn_mfma_f32_32x32x16_f16(za[t2], w2f[t2][0], zacc[0], 0,0,0);
        zacc[1] = __builtin_amdgcn_mfma_f32_32x32x16_f16(za[t2], w2f[t2][1], zacc[1], 0,0,0);
      }
      // prelu(z2)*W3 packed -> LDS -> per-edge dot2 sum
#pragma unroll
      for (int r = 0; r < 16; ++r) {
        f16x2 p = pkrtz(zacc[0][r], zacc[1][r]);
        p = __builtin_elementwise_max(p, p * a2v);
        p = p * w3p;
        C2 cv; cv.h = p;
        int row = (r & 3) + 8*(r >> 2) + 4*h2;
        zb[row*36 + c] = cv.u;
      }
      float ssum = 0.f;
#pragma unroll
      for (int g = 0; g < 4; ++g) {
        H8 v; v.h = *(const f16x8*)((const f16*)zb + (c*36 + 16*h2 + 4*g)*2);
#pragma unroll
        for (int dw = 0; dw < 4; ++dw)
          ssum = fdot2a(v.p[dw], ones2, ssum);
      }
      ssum += __shfl_xor(ssum, 32);
      if (h2 == 0 && valid[m]) out[rbase + 32*m + c] = ssum + b3;
    }
  }
}

extern "C" void kernel_launch(void* const* d_in, const int* in_sizes, int n_in,
                              void* d_out, int out_size, void* d_ws, size_t ws_size,
                              hipStream_t stream) {
  const float* nf  = (const float*)d_in[1];
  const float* sc  = (const float*)d_in[2];
  const float* sm  = (const float*)d_in[3];
  const float* ss  = (const float*)d_in[4];
  const float* We1 = (const float*)d_in[5];
  const float* be1 = (const float*)d_in[6];
  const float* ae1 = (const float*)d_in[7];
  const float* We2 = (const float*)d_in[8];
  const float* be2 = (const float*)d_in[9];
  const float* ae2 = (const float*)d_in[10];
  const float* W1  = (const float*)d_in[11];
  const float* b1  = (const float*)d_in[12];
  const float* a1  = (const float*)d_in[13];
  const float* W2  = (const float*)d_in[14];
  const float* b2  = (const float*)d_in[15];
  const float* a2  = (const float*)d_in[16];
  const float* W3  = (const float*)d_in[17];
  const float* b3  = (const float*)d_in[18];
  const int*   ei  = (const int*)d_in[19];
  const int*   ej  = (const int*)d_in[20];
  float* out = (float*)d_out;

  char* ws = (char*)d_ws;
  float* mpart = (float*)ws;                             // 256 f32 = 1,024 B
  f16*   hbuf = (f16*)(ws + 1024);                       // 1,228,800 B
  u32*   wq   = (u32*)(ws + 1024 + 1228800);             // 143,360 B

  prep_mean_kernel<<<396, 256, 0, stream>>>(We1, We2, W1, W2, sc, wq, mpart);
  enc_kernel<<<200, 256, 0, stream>>>(sc, nf, sm, ss, be1, ae1, be2, ae2,
                                      mpart, wq, hbuf);
  decoder_kernel<<<NBLK, 256, 0, stream>>>(hbuf, wq, b1, b2, a1, a2, W3, b3,
                                           ei, ej, out);
}

// Round 8
// 182.269 us; speedup vs baseline: 1.1664x; 1.1664x over previous
//
#include <hip/hip_runtime.h>

#define NN 400
#define HID 96
#define EDGES 79800
#define BATCH 16
#define ROWS (BATCH*EDGES)
#define NT 13            // node tiles of 32 (tile 12 half-padded)
#define NPAIRS 91        // NT*(NT+1)/2

typedef _Float16 f16;
typedef f16 f16x2 __attribute__((ext_vector_type(2)));
typedef f16 f16x8 __attribute__((ext_vector_type(8)));
typedef __fp16 fp16x2 __attribute__((ext_vector_type(2)));
typedef float f32x16 __attribute__((ext_vector_type(16)));
typedef unsigned int u32;
typedef unsigned long long u64;

union H8 { f16x8 h; u32 u[4]; f16x2 p[4]; fp16x2 q[4]; u64 d[2]; };
union C2 { f16x2 h; fp16x2 q; u32 u; };

__device__ inline f16x2 pkrtz(float a, float b) {
  C2 c; c.q = __builtin_amdgcn_cvt_pkrtz(a, b); return c.h;
}
__device__ inline u32 pkrtz_u(float a, float b) {
  C2 c; c.q = __builtin_amdgcn_cvt_pkrtz(a, b); return c.u;
}
__device__ inline float fdot2a(f16x2 a, f16x2 b, float c) {
#if __has_builtin(__builtin_amdgcn_fdot2)
  C2 ca, cb; ca.h = a; cb.h = b;
  return __builtin_amdgcn_fdot2(ca.q, cb.q, c, false);
#else
  return c + (float)a.x*(float)b.x + (float)a.y*(float)b.y;
#endif
}

__device__ inline f16x8 habs8(f16x8 x) {
  H8 t; t.h = x;
  t.u[0] &= 0x7fff7fffu; t.u[1] &= 0x7fff7fffu;
  t.u[2] &= 0x7fff7fffu; t.u[3] &= 0x7fff7fffu;
  return t.h;
}

__device__ inline f16x8 pack8(float a0,float a1,float a2,float a3,
                              float a4,float a5,float a6,float a7){
  H8 u;
  u.p[0] = pkrtz(a0,a1);
  u.p[1] = pkrtz(a2,a3);
  u.p[2] = pkrtz(a4,a5);
  u.p[3] = pkrtz(a6,a7);
  return u.h;
}

// ---------------- fused prep (blocks 0..139) + per-batch partial mean (blocks 140..395) --------
// wq regions (dwords): Wd1 [0,9216)  Wd2-permK [9216,11264)  We1 [11264,31232)  We2 [31232,35840)
__global__ void prep_mean_kernel(const float* __restrict__ We1, const float* __restrict__ We2,
                                 const float* __restrict__ W1, const float* __restrict__ W2,
                                 const float* __restrict__ sc,
                                 u32* __restrict__ wq, float* __restrict__ mpart) {
  if (blockIdx.x >= 140) {
    int p = blockIdx.x - 140;           // 0..255
    int b = p >> 4, part = p & 15;
    const float4* src = (const float4*)(sc + (size_t)b*160000) + part*2500;
    float s = 0.f;
    for (int i = threadIdx.x; i < 2500; i += 256) {
      float4 v = src[i];
      s += (v.x + v.y) + (v.z + v.w);
    }
    __shared__ float red[256];
    red[threadIdx.x] = s; __syncthreads();
    for (int off = 128; off > 0; off >>= 1) {
      if (threadIdx.x < off) red[threadIdx.x] += red[threadIdx.x + off];
      __syncthreads();
    }
    if (threadIdx.x == 0) mpart[p] = red[0];
    return;
  }
  int D = blockIdx.x*256 + threadIdx.x;     // 0..35839
  float v0, v1;
  if (D < 9216) {               // W_d1 B-frags (288 x 64), d = 32q+c
    int frag = D >> 8;  int t = frag >> 1, q = frag & 1;
    int rem = D & 255;  int lane = rem >> 2, dj = rem & 3;
    int c = lane & 31, h2 = lane >> 5;
    int k = 16*t + 8*h2 + 2*dj;
    int d = 32*q + c;
    v0 = W1[k*64 + d]; v1 = W1[(k+1)*64 + d];
  } else if (D < 11264) {       // W_d2 B-frags, K permuted: pair sources (p, p+32)
    int Dl = D - 9216;
    int frag = Dl >> 8; int t2 = frag >> 1, q = frag & 1;
    int rem = Dl & 255; int lane = rem >> 2, dj = rem & 3;
    int c = lane & 31, h2 = lane >> 5;
    int p = 8*t2 + 4*h2 + dj;
    int d = 32*q + c;
    v0 = W2[p*64 + d]; v1 = W2[(p+32)*64 + d];
  } else if (D < 31232) {       // W_e1 frags (416 x 96), sc features first, static at 400
    int Dl = D - 11264;
    int frag = Dl >> 8; int t = frag/3, ct = frag - 3*t;
    int rem = Dl & 255; int lane = rem >> 2, dj = rem & 3;
    int c = lane & 31, h2 = lane >> 5;
    int k0 = 16*t + 8*h2 + 2*dj, k1 = k0 + 1;
    int d = 32*ct + c;
    v0 = (k0 < 400) ? We1[(8+k0)*96 + d] : (k0 < 408 ? We1[(k0-400)*96 + d] : 0.f);
    v1 = (k1 < 400) ? We1[(8+k1)*96 + d] : (k1 < 408 ? We1[(k1-400)*96 + d] : 0.f);
  } else {                      // W_e2 frags (96 x 96), plain K order
    int Dl = D - 31232;
    int frag = Dl >> 8; int t = frag/3, ct = frag - 3*t;
    int rem = Dl & 255; int lane = rem >> 2, dj = rem & 3;
    int c = lane & 31, h2 = lane >> 5;
    int k = 16*t + 8*h2 + 2*dj;
    int d = 32*ct + c;
    v0 = We2[k*96 + d]; v1 = We2[(k+1)*96 + d];
  }
  wq[D] = pkrtz_u(v0, v1);
}

// ---------------- fused encoder, K-split across 4 waves (R6 form, measured best) ---------------
__global__ __launch_bounds__(256) void enc_kernel(
    const float* __restrict__ sc, const float* __restrict__ nf,
    const float* __restrict__ smean, const float* __restrict__ sstd,
    const float* __restrict__ be1, const float* __restrict__ ae1,
    const float* __restrict__ be2, const float* __restrict__ ae2,
    const float* __restrict__ mpart, const u32* __restrict__ wq,
    f16* __restrict__ hout) {
  __shared__ u32 lds[12288 + 1664];
  const int tid = threadIdx.x;
  const int wid = tid >> 6, lane = tid & 63;
  const int c = lane & 31, h2 = lane >> 5;
  const int r0 = blockIdx.x * 32;
  {
    int row = tid >> 3, seg = tid & 7;
    int r = r0 + row;
    int b = r / 400;
    float ms = 0.f;
    const float4* mp4 = (const float4*)(mpart + 16*b);
#pragma unroll
    for (int k = 0; k < 4; ++k) { float4 v = mp4[k]; ms += (v.x+v.y)+(v.z+v.w); }
    float rm = 1.f / fmaxf(ms*(1.f/160000.f), 1e-8f);
    const float4* src = (const float4*)(sc + (size_t)r*400);
#pragma unroll
    for (int i = 0; i < 13; ++i) {
      int col4 = seg + 8*i;
      if (col4 < 100) {
        float4 v = src[col4];
        u32 lo = pkrtz_u(v.x*rm, v.y*rm);
        u32 hi = pkrtz_u(v.z*rm, v.w*rm);
        *(u64*)(lds + row*210 + col4*2) = (u64)lo | ((u64)hi << 32);
      }
    }
  }
  __syncthreads();
  int tb = (wid==0) ? 0 : (wid==1) ? 7 : (wid==2) ? 14 : 20;
  int te = (wid==0) ? 7 : (wid==1) ? 14 : (wid==2) ? 20 : 26;
  f32x16 acc[3] = {};
  const u32* wb1 = wq + 11264;
  for (int t = tb; t < te; ++t) {
    f16x8 af;
    if (t < 25) {
      H8 av;
      const u32* ap = lds + c*210 + 8*t + 4*h2;
      av.d[0] = *(const u64*)ap;
      av.d[1] = *(const u64*)(ap + 2);
      af = av.h;
    } else {
      af = (f16x8){};
      if (h2 == 0) {
        int r = r0 + c;
        float q0[8];
#pragma unroll
        for (int j = 0; j < 8; ++j)
          q0[j] = (nf[r*8 + j] - smean[j]) / (sstd[j] + 1e-8f);
        af = pack8(q0[0],q0[1],q0[2],q0[3],q0[4],q0[5],q0[6],q0[7]);
      }
    }
#pragma unroll
    for (int ct = 0; ct < 3; ++ct) {
      f16x8 bf = *(const f16x8*)(wb1 + ((t*3+ct)*64 + lane)*4);
      acc[ct] = __builtin_amdgcn_mfma_f32_32x32x16_f16(af, bf, acc[ct], 0,0,0);
    }
  }
  __syncthreads();
#pragma unroll
  for (int ct = 0; ct < 3; ++ct) {
    union { f32x16 v; float4 f[4]; } u; u.v = acc[ct];
#pragma unroll
    for (int i4 = 0; i4 < 4; ++i4)
      *(float4*)(lds + (((wid*3+ct)*4 + i4)*64 + lane)*4) = u.f[i4];
  }
  __syncthreads();
  f16* zb16 = (f16*)(lds + 12288);
  const float a1 = *ae1;
  if (wid < 3) {
    float bv = be1[32*wid + c];
    f32x16 s;
#pragma unroll
    for (int i = 0; i < 16; ++i) s[i] = bv;
#pragma unroll
    for (int w2 = 0; w2 < 4; ++w2) {
#pragma unroll
      for (int i4 = 0; i4 < 4; ++i4) {
        float4 f = *(const float4*)(lds + (((w2*3+wid)*4 + i4)*64 + lane)*4);
        s[4*i4+0] += f.x; s[4*i4+1] += f.y; s[4*i4+2] += f.z; s[4*i4+3] += f.w;
      }
    }
#pragma unroll
    for (int r = 0; r < 16; ++r) {
      float v = s[r]; v = fmaxf(v, a1*v);
      int row = (r & 3) + 8*(r >> 2) + 4*h2;
      zb16[row*104 + 32*wid + c] = (f16)v;
    }
  }
  __syncthreads();
  if (wid < 3) {
    const float a2 = *ae2;
    float bv = be2[32*wid + c];
    f32x16 acc2;
#pragma unroll
    for (int i = 0; i < 16; ++i) acc2[i] = bv;
    const u32* wb2 = wq + 31232;
#pragma unroll
    for (int t = 0; t < 6; ++t) {
      f16x8 af = *(const f16x8*)(zb16 + c*104 + 16*t + 8*h2);
      f16x8 bf = *(const f16x8*)(wb2 + ((t*3+wid)*64 + lane)*4);
      acc2 = __builtin_amdgcn_mfma_f32_32x32x16_f16(af, bf, acc2, 0,0,0);
    }
#pragma unroll
    for (int rr = 0; rr < 16; ++rr) {
      int row = (rr & 3) + 8*(rr >> 2) + 4*h2;
      float v = acc2[rr]; v = fmaxf(v, a2*v);
      hout[(r0 + row)*96 + 32*wid + c] = (f16)v;
    }
  }
}

// ---------------- decoder v2: tile-pair structure (complete-graph edges) ----------------
// Block = (batch b, node-tile pair I<=J). Stage 64 h-rows -> LDS once; all edge features
// built from LDS (no per-edge global gathers, no ei/ej loads — analytic triu index).
// LDS (dwords): hI [0,1536) hJ [1536,3072) wfr16 [3072,11264) zbuf [11264,15872) = 63,488 B.
__global__ __launch_bounds__(256, 2) void decoder_kernel(
    const f16* __restrict__ hbuf, const u32* __restrict__ wq,
    const float* __restrict__ b1, const float* __restrict__ b2,
    const float* __restrict__ ad1, const float* __restrict__ ad2,
    const float* __restrict__ W3, const float* __restrict__ b3p,
    float* __restrict__ out) {
  __shared__ alignas(16) u32 smem[15872];
  const int tid = threadIdx.x;
  // task decode
  int p = blockIdx.x;
  int b = p / NPAIRS, pr = p - b*NPAIRS;
  int I = 0;
  while (pr >= NT - I) { pr -= NT - I; ++I; }
  const int J = I + pr;
  // stage h rows: side 0 = I-tile, side 1 = J-tile (row stride 48 dwords = 96 f16)
  {
    int r = tid >> 2;               // 0..63
    int side = r >> 5, rr = r & 31;
    int nb = (side ? J : I)*32 + rr;
    nb = nb < NN ? nb : NN-1;
    const float4* src = (const float4*)(hbuf + (size_t)(b*NN + nb)*HID) + (tid & 3)*3;
    float4* dst = (float4*)(smem + side*1536 + rr*48) + (tid & 3)*3;
    dst[0] = src[0]; dst[1] = src[1]; dst[2] = src[2];
  }
  // stage Wd1 ksteps 0..15
  {
    float4* dst = (float4*)(smem + 3072);
    const float4* srcw = (const float4*)wq;
    for (int i = tid; i < 2048; i += 256) dst[i] = srcw[i];
  }
  __syncthreads();

  const int lane = tid & 63;
  const int wid  = tid >> 6;
  const int c = lane & 31, h2 = lane >> 5;
  const f16* hI16 = (const f16*)smem;
  const f16* hJrow = (const f16*)(smem + 1536) + c*HID;
  const f16* wfr = (const f16*)(smem + 3072);
  u32* zb = smem + 11264 + wid*1152;
  // register frags: Wd1 ksteps 16,17 (prod t=4,5) + all Wd2
  f16x8 bp4[2], bp5[2];
  bp4[0] = *(const f16x8*)(wq + ((32+0)*64 + lane)*4);
  bp4[1] = *(const f16x8*)(wq + ((32+1)*64 + lane)*4);
  bp5[0] = *(const f16x8*)(wq + ((34+0)*64 + lane)*4);
  bp5[1] = *(const f16x8*)(wq + ((34+1)*64 + lane)*4);
  f16x8 w2f[4][2];
#pragma unroll
  for (int t2 = 0; t2 < 4; ++t2) {
    w2f[t2][0] = *(const f16x8*)(wq + 9216 + ((t2*2+0)*64 + lane)*4);
    w2f[t2][1] = *(const f16x8*)(wq + 9216 + ((t2*2+1)*64 + lane)*4);
  }
  const float b1x = b1[c], b1y = b1[c+32];
  const float b2x = b2[c], b2y = b2[c+32];
  const float a1 = *ad1, a2 = *ad2, b3 = *b3p;
  const f16x2 a1v = pkrtz(a1, a1);
  const f16x2 a2v = pkrtz(a2, a2);
  const f16x2 w3p = pkrtz(W3[c], W3[c+32]);
  const f16x2 ones2 = pkrtz(1.f, 1.f);
  const int gj = J*32 + c;
  const int bofs = b*EDGES;

  for (int it = 0; it < 4; ++it) {
    const int i0 = it*8 + wid*2;                // i_loc for m=0 (m adds 1)
    const f16* hi0 = hI16 + (i0+0)*HID;
    const f16* hi1 = hI16 + (i0+1)*HID;
    f32x16 acc[2][2];
#pragma unroll
    for (int r = 0; r < 16; ++r) {
      acc[0][0][r] = b1x; acc[0][1][r] = b1y;
      acc[1][0][r] = b1x; acc[1][1][r] = b1y;
    }
    // layer 1: K=288 = 6 octet-steps x {sum, absdiff, prod}; everything from LDS/regs
#pragma unroll
    for (int t = 0; t < 6; ++t) {
      f16x8 bs0 = *(const f16x8*)(wfr + (((t   )*2+0)*64 + lane)*8);
      f16x8 bs1 = *(const f16x8*)(wfr + (((t   )*2+1)*64 + lane)*8);
      f16x8 bd0 = *(const f16x8*)(wfr + (((t+ 6)*2+0)*64 + lane)*8);
      f16x8 bd1 = *(const f16x8*)(wfr + (((t+ 6)*2+1)*64 + lane)*8);
      f16x8 bp0 = (t < 4) ? *(const f16x8*)(wfr + (((t+12)*2+0)*64 + lane)*8)
                          : (t == 4 ? bp4[0] : bp5[0]);
      f16x8 bp1 = (t < 4) ? *(const f16x8*)(wfr + (((t+12)*2+1)*64 + lane)*8)
                          : (t == 4 ? bp4[1] : bp5[1]);
      f16x8 hj = *(const f16x8*)(hJrow + 16*t + 8*h2);
#pragma unroll
      for (int m = 0; m < 2; ++m) {
        f16x8 hi = *(const f16x8*)((m ? hi1 : hi0) + 16*t + 8*h2);
        f16x8 su = hi + hj;
        f16x8 di = habs8(hi - hj);
        f16x8 prd = hi * hj;
        acc[m][0] = __builtin_amdgcn_mfma_f32_32x32x16_f16(su, bs0, acc[m][0], 0,0,0);
        acc[m][1] = __builtin_amdgcn_mfma_f32_32x32x16_f16(su, bs1, acc[m][1], 0,0,0);
        acc[m][0] = __builtin_amdgcn_mfma_f32_32x32x16_f16(di, bd0, acc[m][0], 0,0,0);
        acc[m][1] = __builtin_amdgcn_mfma_f32_32x32x16_f16(di, bd1, acc[m][1], 0,0,0);
        acc[m][0] = __builtin_amdgcn_mfma_f32_32x32x16_f16(prd, bp0, acc[m][0], 0,0,0);
        acc[m][1] = __builtin_amdgcn_mfma_f32_32x32x16_f16(prd, bp1, acc[m][1], 0,0,0);
      }
    }
#pragma unroll
    for (int m = 0; m < 2; ++m) {
      // prelu(z1) packed-f16 -> LDS pairs (d, d+32) at dword [row][c], stride 36
#pragma unroll
      for (int r = 0; r < 16; ++r) {
        f16x2 pz = pkrtz(acc[m][0][r], acc[m][1][r]);
        pz = __builtin_elementwise_max(pz, pz * a1v);
        C2 cv; cv.h = pz;
        int row = (r & 3) + 8*(r >> 2) + 4*h2;
        zb[row*36 + c] = cv.u;
      }
      // read back as layer-2 A-frags (edge = c): permuted-K contiguous, aligned b128
      f16x8 za[4];
#pragma unroll
      for (int t2 = 0; t2 < 4; ++t2)
        za[t2] = *(const f16x8*)((const f16*)zb + (c*36 + 8*t2 + 4*h2)*2);
      f32x16 zacc[2];
#pragma unroll
      for (int r = 0; r < 16; ++r) { zacc[0][r] = b2x; zacc[1][r] = b2y; }
#pragma unroll
      for (int t2 = 0; t2 < 4; ++t2) {
        zacc[0] = __builtin_amdgcn_mfma_f32_32x32x16_f16(za[t2], w2f[t2][0], zacc[0], 0,0,0);
        zacc[1] = __builtin_amdgcn_mfma_f32_32x32x16_f16(za[t2], w2f[t2][1], zacc[1], 0,0,0);
      }
      // prelu(z2)*W3 packed -> LDS -> per-edge dot2 sum
#pragma unroll
      for (int r = 0; r < 16; ++r) {
        f16x2 pz = pkrtz(zacc[0][r], zacc[1][r]);
        pz = __builtin_elementwise_max(pz, pz * a2v);
        pz = pz * w3p;
        C2 cv; cv.h = pz;
        int row = (r & 3) + 8*(r >> 2) + 4*h2;
        zb[row*36 + c] = cv.u;
      }
      float ssum = 0.f;
#pragma unroll
      for (int g = 0; g < 4; ++g) {
        H8 v; v.h = *(const f16x8*)((const f16*)zb + (c*36 + 16*h2 + 4*g)*2);
#pragma unroll
        for (int dw = 0; dw < 4; ++dw)
          ssum = fdot2a(v.p[dw], ones2, ssum);
      }
      ssum += __shfl_xor(ssum, 32);
      // lane c holds edge (gi, gj=J*32+c); analytic triu index, coalesced in c
      int gi = I*32 + i0 + m;
      bool valid = (gi < gj) && (gj < NN);
      if (h2 == 0 && valid) {
        int eo = bofs + gi*(799 - gi)/2 + (gj - gi - 1);
        out[eo] = ssum + b3;
      }
    }
  }
}

extern "C" void kernel_launch(void* const* d_in, const int* in_sizes, int n_in,
                              void* d_out, int out_size, void* d_ws, size_t ws_size,
                              hipStream_t stream) {
  const float* nf  = (const float*)d_in[1];
  const float* sc  = (const float*)d_in[2];
  const float* sm  = (const float*)d_in[3];
  const float* ss  = (const float*)d_in[4];
  const float* We1 = (const float*)d_in[5];
  const float* be1 = (const float*)d_in[6];
  const float* ae1 = (const float*)d_in[7];
  const float* We2 = (const float*)d_in[8];
  const float* be2 = (const float*)d_in[9];
  const float* ae2 = (const float*)d_in[10];
  const float* W1  = (const float*)d_in[11];
  const float* b1  = (const float*)d_in[12];
  const float* a1  = (const float*)d_in[13];
  const float* W2  = (const float*)d_in[14];
  const float* b2  = (const float*)d_in[15];
  const float* a2  = (const float*)d_in[16];
  const float* W3  = (const float*)d_in[17];
  const float* b3  = (const float*)d_in[18];
  float* out = (float*)d_out;

  char* ws = (char*)d_ws;
  float* mpart = (float*)ws;                             // 256 f32 = 1,024 B
  f16*   hbuf = (f16*)(ws + 1024);                       // 1,228,800 B
  u32*   wq   = (u32*)(ws + 1024 + 1228800);             // 143,360 B

  prep_mean_kernel<<<396, 256, 0, stream>>>(We1, We2, W1, W2, sc, wq, mpart);
  enc_kernel<<<200, 256, 0, stream>>>(sc, nf, sm, ss, be1, ae1, be2, ae2,
                                      mpart, wq, hbuf);
  decoder_kernel<<<BATCH*NPAIRS, 256, 0, stream>>>(hbuf, wq, b1, b2, a1, a2,
                                                   W3, b3, out);
}